// Round 1
// baseline (437.916 us; speedup 1.0000x reference)
//
#include <hip/hip_runtime.h>
#include <cstdint>

namespace {

constexpr int W = 256;
constexpr int ITERS = 10;
constexpr int PSTR = 260;   // partial row stride (floats): >=256, 16B multiple
constexpr int NG = 8;       // partial groups (after 1-2 shfl pre-combine steps)

// R8: 512 threads (8 waves) -> 128-VGPR budget (the 64-VGPR pin was a
// 16-wave artifact: default waves/EU budget 512/8=64; launch_bounds(512,4)
// gives 512/4=128). Thread (tr=tid>>5 in [0,16), tc=tid&31) owns rows
// [16tr,16tr+16) x cols [8tc,8tc+8). Rows 0..11 in VGPRs (96 floats),
// rows 12..15 in XOR-swizzled LDS (64 KB). Total LDS ~80.0 KB => TWO
// blocks/CU: inter-block overlap hides the barrier/finalize latency chains
// that left VALUBusy at 23%, and all 480 blocks become co-resident (single
// round; HBM load burst overlaps compute of the sibling block).
__global__ __launch_bounds__(512, 4)
void sinkhorn_disp_kernel(
    const float* __restrict__ attn,
    const float* __restrict__ phi_p,
    float* __restrict__ out,
    int nh)
{
  __shared__ __align__(16) float E_lds[512 * 32];   // 64 KB, rows 12..15
  __shared__ __align__(16) float fpart[NG][PSTR];   // 8.3 KB GEMV partials
  __shared__ __align__(16) float eu[W + 4];
  __shared__ __align__(16) float ev[W + 4];
  __shared__ float win[W][3];
  __shared__ int   jmax[W];
  __shared__ float Seu_s, Sev_s, ephi_s;

  const int tid = threadIdx.x;
  const int tc  = tid & 31;                 // col group: cols [8tc, 8tc+8)
  const int tr  = tid >> 5;                 // row group: rows [16tr, 16tr+16)
  const int bid = blockIdx.x;
  const int sw  = tid & 7;                  // chunk swizzle key
  float* myE = &E_lds[tid * 32];
  // chunk c (0..7) <-> tile row 12+(c>>1), cols (c&1)*4 .. +3
  #define RDCH(c) (*(const float4*)&myE[4 * ((c) ^ sw)])

  // ---- load + exp: rows 0..11 -> registers, rows 12..15 -> swizzled LDS ----
  float Er[12][8];
  {
    const float* src = attn + (size_t)bid * (W * W) + (size_t)(tr * 16) * W + tc * 8;
    #pragma unroll
    for (int r = 0; r < 12; ++r) {
      float4 x0 = *(const float4*)(src + r * W);
      float4 x1 = *(const float4*)(src + r * W + 4);
      Er[r][0] = __expf(x0.x); Er[r][1] = __expf(x0.y);
      Er[r][2] = __expf(x0.z); Er[r][3] = __expf(x0.w);
      Er[r][4] = __expf(x1.x); Er[r][5] = __expf(x1.y);
      Er[r][6] = __expf(x1.z); Er[r][7] = __expf(x1.w);
    }
    #pragma unroll
    for (int ap = 0; ap < 4; ++ap) {
      float4 x0 = *(const float4*)(src + (12 + ap) * W);
      float4 x1 = *(const float4*)(src + (12 + ap) * W + 4);
      float4 e0 = make_float4(__expf(x0.x), __expf(x0.y), __expf(x0.z), __expf(x0.w));
      float4 e1 = make_float4(__expf(x1.x), __expf(x1.y), __expf(x1.z), __expf(x1.w));
      *(float4*)&myE[4 * ((2 * ap)     ^ sw)] = e0;
      *(float4*)&myE[4 * ((2 * ap + 1) ^ sw)] = e1;
    }
  }
  if (tid <= W) eu[tid] = 1.0f;            // u0 = 0 -> eu = 1
  if (tid == 0) ephi_s = __expf(phi_p[0]);
  __syncthreads();

  const float inv2w = 1.0f / (2.0f * W);

  for (int it = 0; it < ITERS; ++it) {
    // ---- column pass: cp[b] = sum_r E[16tr+r][8tc+b] * eu[16tr+r] ----
    {
      float cp[8];
      #pragma unroll
      for (int b = 0; b < 8; ++b) cp[b] = 0.0f;
      #pragma unroll
      for (int q = 0; q < 3; ++q) {
        float4 u = *(const float4*)&eu[tr * 16 + q * 4];
        float uu[4] = {u.x, u.y, u.z, u.w};
        #pragma unroll
        for (int k = 0; k < 4; ++k) {
          #pragma unroll
          for (int b = 0; b < 8; ++b)
            cp[b] = __builtin_fmaf(Er[q * 4 + k][b], uu[k], cp[b]);
        }
      }
      {
        float4 u = *(const float4*)&eu[tr * 16 + 12];
        float uu[4] = {u.x, u.y, u.z, u.w};
        #pragma unroll
        for (int ap = 0; ap < 4; ++ap) {
          float4 e0 = RDCH(2 * ap), e1 = RDCH(2 * ap + 1);
          float ua = uu[ap];
          cp[0] = __builtin_fmaf(e0.x, ua, cp[0]);
          cp[1] = __builtin_fmaf(e0.y, ua, cp[1]);
          cp[2] = __builtin_fmaf(e0.z, ua, cp[2]);
          cp[3] = __builtin_fmaf(e0.w, ua, cp[3]);
          cp[4] = __builtin_fmaf(e1.x, ua, cp[4]);
          cp[5] = __builtin_fmaf(e1.y, ua, cp[5]);
          cp[6] = __builtin_fmaf(e1.z, ua, cp[6]);
          cp[7] = __builtin_fmaf(e1.w, ua, cp[7]);
        }
      }
      // combine tr-parity pair (lane <-> lane^32: same tc, tr^1)
      #pragma unroll
      for (int b = 0; b < 8; ++b) cp[b] += __shfl_xor(cp[b], 32, 64);
      if (!(tr & 1)) {
        float4* dst = (float4*)&fpart[tr >> 1][tc * 8];
        dst[0] = make_float4(cp[0], cp[1], cp[2], cp[3]);
        dst[1] = make_float4(cp[4], cp[5], cp[6], cp[7]);
      }
    }
    if (tid < 64) {   // wave 0: Seu = sum_{i<=W} eu_i
      float s = eu[tid] + eu[tid + 64] + eu[tid + 128] + eu[tid + 192];
      if (tid == 0) s += eu[W];
      #pragma unroll
      for (int off = 32; off > 0; off >>= 1) s += __shfl_xor(s, off, 64);
      if (tid == 0) Seu_s = s;
    }
    __syncthreads();
    // ---- column finalize ----
    if (tid < W) {
      float s = 0.0f;
      #pragma unroll
      for (int g = 0; g < NG; ++g) s += fpart[g][tid];
      s += ephi_s * eu[W];
      ev[tid] = inv2w / s;
    } else if (tid == W) {
      ev[W] = 0.5f / (ephi_s * Seu_s);
    }
    __syncthreads();
    // ---- row pass: rp[r] = sum_b E[16tr+r][8tc+b] * ev[8tc+b] ----
    {
      float4 v0 = *(const float4*)&ev[tc * 8];
      float4 v1 = *(const float4*)&ev[tc * 8 + 4];
      float vl[8] = {v0.x, v0.y, v0.z, v0.w, v1.x, v1.y, v1.z, v1.w};
      #pragma unroll
      for (int q = 0; q < 3; ++q) {
        float rp[4];
        #pragma unroll
        for (int k = 0; k < 4; ++k) {
          float s = 0.0f;
          #pragma unroll
          for (int b = 0; b < 8; ++b)
            s = __builtin_fmaf(Er[q * 4 + k][b], vl[b], s);
          rp[k] = s;
        }
        // combine over tc: xor16 then xor8 (stays within 32-lane tc group)
        #pragma unroll
        for (int k = 0; k < 4; ++k) {
          rp[k] += __shfl_xor(rp[k], 16, 64);
          rp[k] += __shfl_xor(rp[k], 8, 64);
        }
        if (tc < 8)
          *(float4*)&fpart[tc][tr * 16 + q * 4] =
              make_float4(rp[0], rp[1], rp[2], rp[3]);
      }
      { // rows 12..15 from LDS chunks
        float rp[4];
        #pragma unroll
        for (int ap = 0; ap < 4; ++ap) {
          float4 e0 = RDCH(2 * ap), e1 = RDCH(2 * ap + 1);
          rp[ap] = e0.x * vl[0] + e0.y * vl[1] + e0.z * vl[2] + e0.w * vl[3]
                 + e1.x * vl[4] + e1.y * vl[5] + e1.z * vl[6] + e1.w * vl[7];
        }
        #pragma unroll
        for (int k = 0; k < 4; ++k) {
          rp[k] += __shfl_xor(rp[k], 16, 64);
          rp[k] += __shfl_xor(rp[k], 8, 64);
        }
        if (tc < 8)
          *(float4*)&fpart[tc][tr * 16 + 12] =
              make_float4(rp[0], rp[1], rp[2], rp[3]);
      }
    }
    if (tid < 64) {   // wave 0: Sev = sum_{j<=W} ev_j
      float s = ev[tid] + ev[tid + 64] + ev[tid + 128] + ev[tid + 192];
      if (tid == 0) s += ev[W];
      #pragma unroll
      for (int off = 32; off > 0; off >>= 1) s += __shfl_xor(s, off, 64);
      if (tid == 0) Sev_s = s;
    }
    __syncthreads();
    // ---- row finalize ----
    if (tid < W) {
      float s = 0.0f;
      #pragma unroll
      for (int g = 0; g < NG; ++g) s += fpart[g][tid];
      s += ephi_s * ev[W];
      eu[tid] = inv2w / s;
    } else if (tid == W) {
      eu[W] = 0.5f / (ephi_s * Sev_s);
    }
    __syncthreads();
  }

  // ---- finale: argmax over P[i][j] ~ E[i][j]*ev[j] + 3-tap window ----
  if (tid < W) { win[tid][0] = 0.0f; win[tid][1] = 0.0f; win[tid][2] = 0.0f; }
  float vl[8];
  {
    float4 v0 = *(const float4*)&ev[tc * 8];
    float4 v1 = *(const float4*)&ev[tc * 8 + 4];
    vl[0] = v0.x; vl[1] = v0.y; vl[2] = v0.z; vl[3] = v0.w;
    vl[4] = v1.x; vl[5] = v1.y; vl[6] = v1.z; vl[7] = v1.w;
  }
  #pragma unroll
  for (int r = 0; r < 16; ++r) {
    float e8[8];
    if (r < 12) {
      #pragma unroll
      for (int b = 0; b < 8; ++b) e8[b] = Er[r < 12 ? r : 0][b];
    } else {
      float4 e0 = RDCH(2 * (r - 12)), e1 = RDCH(2 * (r - 12) + 1);
      e8[0] = e0.x; e8[1] = e0.y; e8[2] = e0.z; e8[3] = e0.w;
      e8[4] = e1.x; e8[5] = e1.y; e8[6] = e1.z; e8[7] = e1.w;
    }
    float m = -1.0f; int mj = 0;
    #pragma unroll
    for (int b = 0; b < 8; ++b) {
      float vv = e8[b] * vl[b];
      if (vv > m) { m = vv; mj = tc * 8 + b; }   // strict > : first max
    }
    // pack (value, first-index-wins); values > 0 so float bits order-preserve
    unsigned long long best =
        (((unsigned long long)__float_as_uint(m)) << 32) |
        (unsigned)(65535 - mj);
    #pragma unroll
    for (int off = 16; off > 0; off >>= 1) {
      unsigned long long o = __shfl_xor(best, off, 64);
      best = (o > best) ? o : best;
    }
    if (tc == 0) jmax[tr * 16 + r] = 65535 - (int)(best & 0xffffffffull);
  }
  __syncthreads();
  // window scatter: unique owner of column j writes P[i][j]
  {
    #pragma unroll
    for (int q = 0; q < 4; ++q) {
      float4 u = *(const float4*)&eu[tr * 16 + q * 4];
      float uu[4] = {u.x, u.y, u.z, u.w};
      #pragma unroll
      for (int k = 0; k < 4; ++k) {
        const int r = q * 4 + k;
        const int i = tr * 16 + r;
        const int jm = jmax[i];
        float e8[8];
        if (r < 12) {
          #pragma unroll
          for (int b = 0; b < 8; ++b) e8[b] = Er[r < 12 ? r : 0][b];
        } else {
          float4 e0 = RDCH(2 * (r - 12)), e1 = RDCH(2 * (r - 12) + 1);
          e8[0] = e0.x; e8[1] = e0.y; e8[2] = e0.z; e8[3] = e0.w;
          e8[4] = e1.x; e8[5] = e1.y; e8[6] = e1.z; e8[7] = e1.w;
        }
        #pragma unroll
        for (int b = 0; b < 8; ++b) {
          int kk = (tc * 8 + b) - (jm - 1);
          if (kk >= 0 && kk < 3) {
            win[i][kk] = e8[b] * vl[b] * uu[k] * (2.0f * W);
          }
        }
      }
    }
  }
  __syncthreads();
  if (tid < W) {
    const int i  = tid;
    const int jm = jmax[i];
    float w0 = win[i][0], w1 = win[i][1], w2 = win[i][2];
    float norm0 = w0 + w1 + w2;
    float norm  = (norm0 < 0.1f) ? 1.0f : norm0;
    float p0 = fmaxf((float)(i - (jm - 1)), 0.0f);
    float p1 = fmaxf((float)(i - jm),       0.0f);
    float p2 = fmaxf((float)(i - (jm + 1)), 0.0f);
    float disp = (w0 / norm) * p0 + (w1 / norm) * p1 + (w2 / norm) * p2;
    float occ  = 1.0f - norm;
    out[(size_t)bid * W + i] = disp;
    out[(size_t)nh * W + (size_t)bid * W + i] = occ;
  }
  #undef RDCH
}

} // namespace

extern "C" void kernel_launch(void* const* d_in, const int* in_sizes, int n_in,
                              void* d_out, int out_size, void* d_ws, size_t ws_size,
                              hipStream_t stream) {
  (void)n_in; (void)d_ws; (void)ws_size; (void)out_size;
  const float* attn = (const float*)d_in[0];
  const float* phi  = (const float*)d_in[1];
  float* out = (float*)d_out;
  const int nh = in_sizes[0] / (W * W);   // 4*120 = 480 matrices
  sinkhorn_disp_kernel<<<dim3(nh), dim3(512), 0, stream>>>(attn, phi, out, nh);
}

// Round 2
// 369.535 us; speedup vs baseline: 1.1850x; 1.1850x over previous
//
#include <hip/hip_runtime.h>
#include <cstdint>

namespace {

constexpr int W = 256;
constexpr int ITERS = 10;
constexpr int PSTR = 260;   // partial row stride (floats): >=256, 16B multiple
constexpr int NG = 16;      // partial groups (after in-wave shfl pre-combine)

// R9: the "64-VGPR pin" was the compiler's DEFAULT occupancy target
// (8 waves/EU -> 512/8 = 64). R8's spill arithmetic (~35 floats * 20 reloads
// = 683 MB extra FETCH) proves launch_bounds(...,4) moves the cap to 128.
// So: keep R7's 1024-thread 8x8-tile geometry, declare (1024,4), and hold
// the WHOLE tile (64 floats) in VGPRs. No E in LDS at all: GEMV inner loops
// are pure-register FMA, LDS shrinks to ~27 KB (fpart/eu/ev/win/jmax).
// 1 block/CU (register file full) -- same as R7, but the per-iteration
// critical path loses all ds_read E traffic.
__global__ __launch_bounds__(1024, 4)
void sinkhorn_disp_kernel(
    const float* __restrict__ attn,
    const float* __restrict__ phi_p,
    float* __restrict__ out,
    int nh)
{
  __shared__ __align__(16) float fpart[NG][PSTR];   // 16.6 KB GEMV partials
  __shared__ __align__(16) float eu[W + 4];
  __shared__ __align__(16) float ev[W + 4];
  __shared__ float win[W][3];
  __shared__ int   jmax[W];
  __shared__ float Seu_s, Sev_s, ephi_s;

  const int tid = threadIdx.x;
  const int tc  = tid & 31;                 // col group: cols [8tc, 8tc+8)
  const int tr  = tid >> 5;                 // row group: rows [8tr, 8tr+8)
  const int bid = blockIdx.x;

  // ---- load + exp: all 8 tile rows -> registers ----
  float Er[8][8];
  {
    const float* src = attn + (size_t)bid * (W * W) + (size_t)(tr * 8) * W + tc * 8;
    #pragma unroll
    for (int a = 0; a < 8; ++a) {
      float4 x0 = *(const float4*)(src + a * W);
      float4 x1 = *(const float4*)(src + a * W + 4);
      Er[a][0] = __expf(x0.x); Er[a][1] = __expf(x0.y);
      Er[a][2] = __expf(x0.z); Er[a][3] = __expf(x0.w);
      Er[a][4] = __expf(x1.x); Er[a][5] = __expf(x1.y);
      Er[a][6] = __expf(x1.z); Er[a][7] = __expf(x1.w);
    }
  }
  if (tid <= W) eu[tid] = 1.0f;            // u0 = 0 -> eu = 1
  if (tid == 0) ephi_s = __expf(phi_p[0]);
  __syncthreads();

  const float inv2w = 1.0f / (2.0f * W);

  for (int it = 0; it < ITERS; ++it) {
    // ---- column pass: cp[b] = sum_a E[8tr+a][8tc+b] * eu[8tr+a] ----
    {
      float4 u0 = *(const float4*)&eu[tr * 8];
      float4 u1 = *(const float4*)&eu[tr * 8 + 4];
      float ul[8] = {u0.x, u0.y, u0.z, u0.w, u1.x, u1.y, u1.z, u1.w};
      float cp[8];
      #pragma unroll
      for (int b = 0; b < 8; ++b) cp[b] = 0.0f;
      #pragma unroll
      for (int a = 0; a < 8; ++a) {
        #pragma unroll
        for (int b = 0; b < 8; ++b)
          cp[b] = __builtin_fmaf(Er[a][b], ul[a], cp[b]);
      }
      // combine tr-parity pair (lane <-> lane^32: same tc, tr^1)
      #pragma unroll
      for (int b = 0; b < 8; ++b) cp[b] += __shfl_xor(cp[b], 32, 64);
      if (!(tr & 1)) {
        float4* dst = (float4*)&fpart[tr >> 1][tc * 8];
        dst[0] = make_float4(cp[0], cp[1], cp[2], cp[3]);
        dst[1] = make_float4(cp[4], cp[5], cp[6], cp[7]);
      }
    }
    if (tid < 64) {   // wave 0: Seu = sum_{i<=W} eu_i
      float s = eu[tid] + eu[tid + 64] + eu[tid + 128] + eu[tid + 192];
      if (tid == 0) s += eu[W];
      #pragma unroll
      for (int off = 32; off > 0; off >>= 1) s += __shfl_xor(s, off, 64);
      if (tid == 0) Seu_s = s;
    }
    __syncthreads();
    // ---- column finalize ----
    if (tid < W) {
      float s = 0.0f;
      #pragma unroll
      for (int g = 0; g < NG; ++g) s += fpart[g][tid];
      s += ephi_s * eu[W];
      ev[tid] = inv2w / s;
    } else if (tid == W) {
      ev[W] = 0.5f / (ephi_s * Seu_s);
    }
    __syncthreads();
    // ---- row pass: rp[a] = sum_b E[8tr+a][8tc+b] * ev[8tc+b] ----
    {
      float4 v0 = *(const float4*)&ev[tc * 8];
      float4 v1 = *(const float4*)&ev[tc * 8 + 4];
      float vl[8] = {v0.x, v0.y, v0.z, v0.w, v1.x, v1.y, v1.z, v1.w};
      float rp[8];
      #pragma unroll
      for (int a = 0; a < 8; ++a) {
        float s = 0.0f;
        #pragma unroll
        for (int b = 0; b < 8; ++b)
          s = __builtin_fmaf(Er[a][b], vl[b], s);
        rp[a] = s;
      }
      // combine tc-halves (lane <-> lane^16: same rows, tc^16)
      #pragma unroll
      for (int a = 0; a < 8; ++a) rp[a] += __shfl_xor(rp[a], 16, 64);
      if (!(tc & 16)) {
        float4* dst = (float4*)&fpart[tc][tr * 8];
        dst[0] = make_float4(rp[0], rp[1], rp[2], rp[3]);
        dst[1] = make_float4(rp[4], rp[5], rp[6], rp[7]);
      }
    }
    if (tid < 64) {   // wave 0: Sev = sum_{j<=W} ev_j
      float s = ev[tid] + ev[tid + 64] + ev[tid + 128] + ev[tid + 192];
      if (tid == 0) s += ev[W];
      #pragma unroll
      for (int off = 32; off > 0; off >>= 1) s += __shfl_xor(s, off, 64);
      if (tid == 0) Sev_s = s;
    }
    __syncthreads();
    // ---- row finalize ----
    if (tid < W) {
      float s = 0.0f;
      #pragma unroll
      for (int g = 0; g < NG; ++g) s += fpart[g][tid];
      s += ephi_s * ev[W];
      eu[tid] = inv2w / s;
    } else if (tid == W) {
      eu[W] = 0.5f / (ephi_s * Sev_s);
    }
    __syncthreads();
  }

  // ---- finale: argmax over P[i][j] ~ E[i][j]*ev[j] + 3-tap window ----
  if (tid < W) { win[tid][0] = 0.0f; win[tid][1] = 0.0f; win[tid][2] = 0.0f; }
  float vl[8];
  {
    float4 v0 = *(const float4*)&ev[tc * 8];
    float4 v1 = *(const float4*)&ev[tc * 8 + 4];
    vl[0] = v0.x; vl[1] = v0.y; vl[2] = v0.z; vl[3] = v0.w;
    vl[4] = v1.x; vl[5] = v1.y; vl[6] = v1.z; vl[7] = v1.w;
  }
  #pragma unroll
  for (int a = 0; a < 8; ++a) {
    float m = -1.0f; int mj = 0;
    #pragma unroll
    for (int b = 0; b < 8; ++b) {
      float vv = Er[a][b] * vl[b];
      if (vv > m) { m = vv; mj = tc * 8 + b; }   // strict > : first max
    }
    // pack (value, first-index-wins); values > 0 so float bits order-preserve
    unsigned long long best =
        (((unsigned long long)__float_as_uint(m)) << 32) |
        (unsigned)(65535 - mj);
    #pragma unroll
    for (int off = 16; off > 0; off >>= 1) {
      unsigned long long o = __shfl_xor(best, off, 64);
      best = (o > best) ? o : best;
    }
    if (tc == 0) jmax[tr * 8 + a] = 65535 - (int)(best & 0xffffffffull);
  }
  __syncthreads();
  // window scatter: unique owner of column j writes P[i][j]
  {
    float4 u0 = *(const float4*)&eu[tr * 8];
    float4 u1 = *(const float4*)&eu[tr * 8 + 4];
    float ul[8] = {u0.x, u0.y, u0.z, u0.w, u1.x, u1.y, u1.z, u1.w};
    #pragma unroll
    for (int a = 0; a < 8; ++a) {
      const int i  = tr * 8 + a;
      const int jm = jmax[i];
      #pragma unroll
      for (int b = 0; b < 8; ++b) {
        int k = (tc * 8 + b) - (jm - 1);
        if (k >= 0 && k < 3) {
          win[i][k] = Er[a][b] * vl[b] * ul[a] * (2.0f * W);
        }
      }
    }
  }
  __syncthreads();
  if (tid < W) {
    const int i  = tid;
    const int jm = jmax[i];
    float w0 = win[i][0], w1 = win[i][1], w2 = win[i][2];
    float norm0 = w0 + w1 + w2;
    float norm  = (norm0 < 0.1f) ? 1.0f : norm0;
    float p0 = fmaxf((float)(i - (jm - 1)), 0.0f);
    float p1 = fmaxf((float)(i - jm),       0.0f);
    float p2 = fmaxf((float)(i - (jm + 1)), 0.0f);
    float disp = (w0 / norm) * p0 + (w1 / norm) * p1 + (w2 / norm) * p2;
    float occ  = 1.0f - norm;
    out[(size_t)bid * W + i] = disp;
    out[(size_t)nh * W + (size_t)bid * W + i] = occ;
  }
}

} // namespace

extern "C" void kernel_launch(void* const* d_in, const int* in_sizes, int n_in,
                              void* d_out, int out_size, void* d_ws, size_t ws_size,
                              hipStream_t stream) {
  (void)n_in; (void)d_ws; (void)ws_size; (void)out_size;
  const float* attn = (const float*)d_in[0];
  const float* phi  = (const float*)d_in[1];
  float* out = (float*)d_out;
  const int nh = in_sizes[0] / (W * W);   // 4*120 = 480 matrices
  sinkhorn_disp_kernel<<<dim3(nh), dim3(1024), 0, stream>>>(attn, phi, out, nh);
}